// Round 3
// baseline (459.329 us; speedup 1.0000x reference)
//
#include <hip/hip_runtime.h>
#include <hip/hip_bf16.h>
#include <stdint.h>

#define NROW 8192
#define NCOL 8192
#define INF 256
#define OUTF 256

typedef __attribute__((ext_vector_type(4))) float f32x4;
typedef __attribute__((ext_vector_type(8))) short s16x8;
typedef __attribute__((ext_vector_type(4))) int i32x4;
typedef __attribute__((ext_vector_type(2))) unsigned int u32x2;

__device__ __forceinline__ short f2bf(float f) {
  unsigned int u = __builtin_bit_cast(unsigned int, f);
  unsigned int r = (u + 0x7FFFu + ((u >> 16) & 1u)) >> 16;  // RTNE
  return (short)r;
}
__device__ __forceinline__ float bf2f(short s) {
  unsigned int u = ((unsigned int)(unsigned short)s) << 16;
  return __builtin_bit_cast(float, u);
}
__device__ __forceinline__ unsigned int pkbf(float lo, float hi) {
#if __has_builtin(__builtin_amdgcn_cvt_pk_bf16_f32)
  auto t = __builtin_amdgcn_cvt_pk_bf16_f32(lo, hi);
  return __builtin_bit_cast(unsigned int, t);
#else
  unsigned int r;
  asm("v_cvt_pk_bf16_f32 %0, %1, %2" : "=v"(r) : "v"(lo), "v"(hi));
  return r;
#endif
}

#define GLDS(g, l)                                                            \
  __builtin_amdgcn_global_load_lds(                                           \
      (const __attribute__((address_space(1))) void*)(g),                     \
      (__attribute__((address_space(3))) void*)(l), 16, 0, 0)

// ---------------------------------------------------------------------------
// K1: dis[i] = 1/sqrt(1 + sum_j A[i,j]) AND Abf = bf16(A) (RTNE via pkbf —
// identical rounding to the old in-GEMM ldcvt, so downstream MFMA inputs are
// bit-identical). One wave per row, 4 rows/block; 8-B stores, 512 B/wave/iter.
// ---------------------------------------------------------------------------
__global__ __launch_bounds__(256) void k_deg(const float* __restrict__ A,
                                             float* __restrict__ dis,
                                             short* __restrict__ Abf) {
  const int wave = threadIdx.x >> 6, lane = threadIdx.x & 63;
  const int row = (blockIdx.x << 2) + wave;
  const f32x4* Ar = (const f32x4*)(A + (size_t)row * NCOL);
  u32x2* Br = (u32x2*)(Abf + (size_t)row * NCOL);
  float s = 0.f;
#pragma unroll 8
  for (int it = 0; it < 32; ++it) {
    f32x4 v = Ar[(it << 6) + lane];
    u32x2 pk;
    pk.x = pkbf(v.x, v.y);
    pk.y = pkbf(v.z, v.w);
    Br[(it << 6) + lane] = pk;
    s += (v.x + v.y) + (v.z + v.w);
  }
#pragma unroll
  for (int off = 32; off > 0; off >>= 1) s += __shfl_down(s, off, 64);
  if (lane == 0) dis[row] = 1.0f / sqrtf(s + 1.0f);
}

// ---------------------------------------------------------------------------
// K2: Z = d ⊙ (X @ W^T)  [8192 x 256], bf16 MFMA, fp32 acc.
// Associativity: out = Anorm@(X@W^T)+b, so the 256x256 W-GEMM happens ONCE
// here instead of inside the big-N epilogue.
// Outputs: Ztf (MFMA-B fragment order, feeds k_gemm) and Zrm (row-major,
// for the +I term in k_fin).
// Block: 32 j-rows x 256 o-cols, 4 waves (wave w = o-strip of 64).
// ---------------------------------------------------------------------------
__global__ __launch_bounds__(256) void k_z(const float* __restrict__ X,
                                           const float* __restrict__ W,
                                           const float* __restrict__ dis,
                                           short* __restrict__ Ztf,
                                           short* __restrict__ Zrm) {
  __shared__ float sd[32];
  const int tid = threadIdx.x;
  const int w = tid >> 6, l = tid & 63, lr = l & 15, lq = l >> 4;
  const int jb = (int)blockIdx.x << 5;
  if (tid < 32) sd[tid] = dis[jb + tid];
  __syncthreads();

  f32x4 acc[2][4];
#pragma unroll
  for (int rt = 0; rt < 2; ++rt)
#pragma unroll
    for (int ct = 0; ct < 4; ++ct) acc[rt][ct] = (f32x4){0.f, 0.f, 0.f, 0.f};

  for (int s = 0; s < 8; ++s) {
    const int f0 = (s << 5) + (lq << 3);
    s16x8 bf[4];
#pragma unroll
    for (int ct = 0; ct < 4; ++ct) {  // B-frag: n = o, k = f
      const float* wp = W + (size_t)((w << 6) + (ct << 4) + lr) * INF + f0;
      f32x4 u0 = *(const f32x4*)(wp);
      f32x4 u1 = *(const f32x4*)(wp + 4);
      i32x4 t;
      t.x = (int)pkbf(u0.x, u0.y); t.y = (int)pkbf(u0.z, u0.w);
      t.z = (int)pkbf(u1.x, u1.y); t.w = (int)pkbf(u1.z, u1.w);
      bf[ct] = __builtin_bit_cast(s16x8, t);
    }
#pragma unroll
    for (int rt = 0; rt < 2; ++rt) {  // A-frag: m = j, k = f, scaled by d_j
      const int jl = (rt << 4) + lr;
      const float* xp = X + (size_t)(jb + jl) * INF + f0;
      const float d = sd[jl];
      f32x4 u0 = *(const f32x4*)(xp);
      f32x4 u1 = *(const f32x4*)(xp + 4);
      i32x4 t;
      t.x = (int)pkbf(u0.x * d, u0.y * d); t.y = (int)pkbf(u0.z * d, u0.w * d);
      t.z = (int)pkbf(u1.x * d, u1.y * d); t.w = (int)pkbf(u1.z * d, u1.w * d);
      const s16x8 af = __builtin_bit_cast(s16x8, t);
#pragma unroll
      for (int ct = 0; ct < 4; ++ct)
        acc[rt][ct] = __builtin_amdgcn_mfma_f32_16x16x32_bf16(
            af, bf[ct], acc[rt][ct], 0, 0, 0);
    }
  }

  // D-frag: lane l holds (j = jb + rt*16 + lq*4 + r, o = w*64 + ct*16 + lr)
#pragma unroll
  for (int rt = 0; rt < 2; ++rt)
#pragma unroll
    for (int ct = 0; ct < 4; ++ct) {
      const int o = (w << 6) + (ct << 4) + lr;
      // Ztf: frag(ft = o>>4 = w*4+ct, kb = j>>5 = blockIdx.x);
      // lane' = (o&15) + 16*((j&31)>>3); elem = j&7 -> 4 consecutive (lq&1)*4+r
      const int lane2 = lr + (((rt << 1) + (lq >> 1)) << 4);
      u32x2 p;
      p.x = pkbf(acc[rt][ct].x, acc[rt][ct].y);
      p.y = pkbf(acc[rt][ct].z, acc[rt][ct].w);
      const size_t dst = (((size_t)((w << 2) + ct) << 8) + blockIdx.x) * 512 +
                         (lane2 << 3) + ((lq & 1) << 2);
      *(u32x2*)(Ztf + dst) = p;
      // Zrm: row-major scatter (tiny kernel, 2-B stores)
      const int jrow = jb + (rt << 4) + (lq << 2);
#pragma unroll
      for (int r = 0; r < 4; ++r)
        Zrm[(size_t)(jrow + r) * OUTF + o] = f2bf(acc[rt][ct][r]);
    }
}

// ---------------------------------------------------------------------------
// K3: P[sp] = Abf[64 rows, ksp] @ Ztf^T  (bf16 MFMA, fp32 acc).
// A is now PRE-CONVERTED bf16 (written by k_deg): halves the A-read traffic
// (134 MB, mostly L3-resident after k_deg's write-through) and eliminates the
// 128 cvt_pk per thread per K-step — LDS fragments feed MFMA directly.
// BM=64 BN=256 BK=128; GLDS linear-dest staging with pre-swizzled source
// (chunk c' = c ^ (n&7), involution applied on both store-source and read);
// B via coalesced frag-ordered loads from L2-resident Ztf, 1-slot-ahead
// rotation. Same bf16 values, same k-slot order => bit-identical numerics.
// ---------------------------------------------------------------------------
__global__ __launch_bounds__(256, 2) void k_gemm(const short* __restrict__ Abf,
                                                 const short* __restrict__ Ztf,
                                                 float* __restrict__ P,
                                                 int splits) {
  __shared__ short Ab[2 * 8192];  // 2 x (64 rows x 128 bf16), chunk-swizzled
  const int tid = threadIdx.x;
  const int w = tid >> 6, l = tid & 63, lr = l & 15, lq = l >> 4;
  const int row0 = (int)blockIdx.x << 6;
  const int sp = blockIdx.y;
  const int kspan = NCOL / splits;
  const int k0 = sp * kspan;
  const int steps = kspan >> 7;   // BK = 128
  const int slots = kspan >> 5;   // 32-wide B k-slots per split

  // staging map: LDS byte L = j*4096 + tid*16 (linear for GLDS);
  // L encodes row n = j*16 + (tid>>4) (256 B/row), chunk c = tid&15.
  // stored content = global chunk c' = c ^ (n&7)  (j*16 doesn't affect n&7).
  const int n_ = tid >> 4;
  const int cs = (tid & 15) ^ (n_ & 7);
  const char* gA[4];
#pragma unroll
  for (int j = 0; j < 4; ++j) {
    const int n = (j << 4) + n_;
    gA[j] = (const char*)Abf + (((size_t)(row0 + n)) << 14) +
            ((size_t)k0 << 1) + (cs << 4);
  }
  char* ldst0 = (char*)Ab + ((tid & ~63) << 4);

  // frag-ordered B: frag (ftile = w*4+ct, kb) at Ztf[(ftile*256+kb)*512 + l*8]
  const short* Bw = Ztf + ((size_t)w << 19) + ((size_t)(k0 >> 5) << 9) + (l << 3);

  f32x4 acc[4][4];
#pragma unroll
  for (int rt = 0; rt < 4; ++rt)
#pragma unroll
    for (int ct = 0; ct < 4; ++ct) acc[rt][ct] = (f32x4){0.f, 0.f, 0.f, 0.f};

  // prologue: DMA(0); B slot 0
#pragma unroll
  for (int j = 0; j < 4; ++j) GLDS(gA[j], ldst0 + (j << 12));
  i32x4 bCur[4], bNxt[4];
#pragma unroll
  for (int ct = 0; ct < 4; ++ct)
    bCur[ct] = *(const i32x4*)(Bw + ((size_t)ct << 17));

  for (int s = 0; s < steps; ++s) {
    __syncthreads();  // drains DMA(s) + any in-flight B prefetch

    if (s + 1 < steps) {
      char* dst = ldst0 + (((s + 1) & 1) << 14);  // 16 KB buffers
      const size_t go = (size_t)(s + 1) << 8;     // 256 B = 128 bf16
#pragma unroll
      for (int j = 0; j < 4; ++j) GLDS(gA[j] + go, dst + (j << 12));
    }

    const char* buf = (const char*)Ab + ((s & 1) << 14);

#pragma unroll
    for (int kc = 0; kc < 4; ++kc) {
      // rotate in next B slot (g = s*4+kc+1), coalesced from L2
      int gn = (s << 2) + kc + 1;
      if (gn >= slots) gn = 0;  // harmless wrap on the final prefetch
#pragma unroll
      for (int ct = 0; ct < 4; ++ct)
        bNxt[ct] = *(const i32x4*)(Bw + ((size_t)ct << 17) + ((size_t)gn << 9));

      s16x8 af[4];
#pragma unroll
      for (int rt = 0; rt < 4; ++rt) {
        const int n = (rt << 4) + lr;
        const int cc = (kc << 2) | lq;
        af[rt] = *(const s16x8*)(buf + (n << 8) + ((cc ^ (n & 7)) << 4));
      }
#pragma unroll
      for (int rt = 0; rt < 4; ++rt) {
        const s16x8 a = af[rt];
#pragma unroll
        for (int ct = 0; ct < 4; ++ct)
          acc[rt][ct] = __builtin_amdgcn_mfma_f32_16x16x32_bf16(
              a, __builtin_bit_cast(s16x8, bCur[ct]), acc[rt][ct], 0, 0, 0);
      }
#pragma unroll
      for (int ct = 0; ct < 4; ++ct) bCur[ct] = bNxt[ct];
    }
  }

  float* Pp = P + ((size_t)sp << 21);
#pragma unroll
  for (int rt = 0; rt < 4; ++rt)
#pragma unroll
    for (int ct = 0; ct < 4; ++ct) {
      const int col = (w << 6) + (ct << 4) + lr;
      const int row = row0 + (rt << 4) + (lq << 2);
#pragma unroll
      for (int r = 0; r < 4; ++r)
        Pp[((size_t)(row + r) << 8) + col] = acc[rt][ct][r];
    }
}

// ---------------------------------------------------------------------------
// K4: out[i,o] = dis[i]*(sum_sp P + Z[i,o]) + b[o]  — pure coalesced reduce.
// One f32x4 per thread; a wave covers exactly one row (dis wave-uniform).
// ---------------------------------------------------------------------------
__global__ __launch_bounds__(256) void k_fin(const float* __restrict__ P,
                                             const short* __restrict__ Zrm,
                                             const float* __restrict__ dis,
                                             const float* __restrict__ bias,
                                             float* __restrict__ out,
                                             int splits) {
  const int q = (int)blockIdx.x * 256 + threadIdx.x;
  const int i = q >> 6;
  const int o0 = (q & 63) << 2;
  const float di = dis[i];
  const float* p = P + ((size_t)i << 8) + o0;
  f32x4 u = *(const f32x4*)p;
#pragma unroll 3
  for (int sp = 1; sp < 4; ++sp) u += *(const f32x4*)(p + ((size_t)sp << 21));
  u32x2 zz = *(const u32x2*)(Zrm + ((size_t)i << 8) + o0);
  f32x4 z;
  z.x = bf2f((short)(zz.x & 0xFFFF));
  z.y = bf2f((short)(zz.x >> 16));
  z.z = bf2f((short)(zz.y & 0xFFFF));
  z.w = bf2f((short)(zz.y >> 16));
  f32x4 bb = *(const f32x4*)(bias + o0);
  f32x4 r = (u + z) * di + bb;
  *(f32x4*)(out + ((size_t)i << 8) + o0) = r;
}

// ---------------------------------------------------------------------------
extern "C" void kernel_launch(void* const* d_in, const int* in_sizes, int n_in,
                              void* d_out, int out_size, void* d_ws,
                              size_t ws_size, hipStream_t stream) {
  const float* X = (const float*)d_in[0];
  const float* A = (const float*)d_in[1];
  const float* W = (const float*)d_in[2];
  const float* b = (const float*)d_in[3];
  float* out = (float*)d_out;

  char* ws = (char*)d_ws;
  float* dis = (float*)ws;                         // 32 KB
  short* Ztf = (short*)(ws + 32768);               // 4 MB (frag-ordered Z)
  short* Zrm = (short*)(ws + 32768 + 4194304);     // 4 MB (row-major Z)
  float* P = (float*)(ws + 32768 + 2 * 4194304);   // 4 x 8 MB split-K partials
  short* Abf = (short*)(ws + 32768 + 2 * 4194304 + 4 * 8388608);  // 128 MB

  k_deg<<<2048, 256, 0, stream>>>(A, dis, Abf);
  k_z<<<256, 256, 0, stream>>>(X, W, dis, Ztf, Zrm);
  k_gemm<<<dim3(128, 4), 256, 0, stream>>>(Abf, Ztf, P, 4);
  k_fin<<<2048, 256, 0, stream>>>(P, Zrm, dis, b, out, 4);
}

// Round 4
// 451.048 us; speedup vs baseline: 1.0184x; 1.0184x over previous
//
#include <hip/hip_runtime.h>
#include <hip/hip_bf16.h>
#include <stdint.h>

#define NROW 8192
#define NCOL 8192
#define INF 256
#define OUTF 256

typedef __attribute__((ext_vector_type(4))) float f32x4;
typedef __attribute__((ext_vector_type(8))) short s16x8;
typedef __attribute__((ext_vector_type(4))) int i32x4;
typedef __attribute__((ext_vector_type(2))) unsigned int u32x2;

__device__ __forceinline__ short f2bf(float f) {
  unsigned int u = __builtin_bit_cast(unsigned int, f);
  unsigned int r = (u + 0x7FFFu + ((u >> 16) & 1u)) >> 16;  // RTNE
  return (short)r;
}
__device__ __forceinline__ float bf2f(short s) {
  unsigned int u = ((unsigned int)(unsigned short)s) << 16;
  return __builtin_bit_cast(float, u);
}
__device__ __forceinline__ unsigned int pkbf(float lo, float hi) {
#if __has_builtin(__builtin_amdgcn_cvt_pk_bf16_f32)
  auto t = __builtin_amdgcn_cvt_pk_bf16_f32(lo, hi);
  return __builtin_bit_cast(unsigned int, t);
#else
  unsigned int r;
  asm("v_cvt_pk_bf16_f32 %0, %1, %2" : "=v"(r) : "v"(lo), "v"(hi));
  return r;
#endif
}

#define GLDS(g, l)                                                            \
  __builtin_amdgcn_global_load_lds(                                           \
      (const __attribute__((address_space(1))) void*)(g),                     \
      (__attribute__((address_space(3))) void*)(l), 16, 0, 0)

// ---------------------------------------------------------------------------
// K1: dis[i] = 1/sqrt(1 + sum_j A[i,j]); one wave per row, 4 rows/block
// (pure-read version — R3 showed the fused Abf write costs more in k_deg
//  than it saves in k_gemm)
// ---------------------------------------------------------------------------
__global__ __launch_bounds__(256) void k_deg(const float* __restrict__ A,
                                             float* __restrict__ dis) {
  const int wave = threadIdx.x >> 6, lane = threadIdx.x & 63;
  const int row = (blockIdx.x << 2) + wave;
  const f32x4* Ar = (const f32x4*)(A + (size_t)row * NCOL);
  float s = 0.f;
#pragma unroll 8
  for (int it = 0; it < 32; ++it) {
    f32x4 v = Ar[(it << 6) + lane];
    s += (v.x + v.y) + (v.z + v.w);
  }
#pragma unroll
  for (int off = 32; off > 0; off >>= 1) s += __shfl_down(s, off, 64);
  if (lane == 0) dis[row] = 1.0f / sqrtf(s + 1.0f);
}

// ---------------------------------------------------------------------------
// K2: Z = d ⊙ (X @ W^T)  [8192 x 256], bf16 MFMA, fp32 acc.
// Associativity: out = Anorm@(X@W^T)+b, so the 256x256 W-GEMM happens ONCE
// here instead of inside the big-N epilogue.
// Outputs: Ztf (MFMA-B fragment order, feeds k_gemm) and Zrm (row-major,
// for the +I term in k_fin).
// Block: 32 j-rows x 256 o-cols, 4 waves (wave w = o-strip of 64).
// ---------------------------------------------------------------------------
__global__ __launch_bounds__(256) void k_z(const float* __restrict__ X,
                                           const float* __restrict__ W,
                                           const float* __restrict__ dis,
                                           short* __restrict__ Ztf,
                                           short* __restrict__ Zrm) {
  __shared__ float sd[32];
  const int tid = threadIdx.x;
  const int w = tid >> 6, l = tid & 63, lr = l & 15, lq = l >> 4;
  const int jb = (int)blockIdx.x << 5;
  if (tid < 32) sd[tid] = dis[jb + tid];
  __syncthreads();

  f32x4 acc[2][4];
#pragma unroll
  for (int rt = 0; rt < 2; ++rt)
#pragma unroll
    for (int ct = 0; ct < 4; ++ct) acc[rt][ct] = (f32x4){0.f, 0.f, 0.f, 0.f};

  for (int s = 0; s < 8; ++s) {
    const int f0 = (s << 5) + (lq << 3);
    s16x8 bf[4];
#pragma unroll
    for (int ct = 0; ct < 4; ++ct) {  // B-frag: n = o, k = f
      const float* wp = W + (size_t)((w << 6) + (ct << 4) + lr) * INF + f0;
      f32x4 u0 = *(const f32x4*)(wp);
      f32x4 u1 = *(const f32x4*)(wp + 4);
      i32x4 t;
      t.x = (int)pkbf(u0.x, u0.y); t.y = (int)pkbf(u0.z, u0.w);
      t.z = (int)pkbf(u1.x, u1.y); t.w = (int)pkbf(u1.z, u1.w);
      bf[ct] = __builtin_bit_cast(s16x8, t);
    }
#pragma unroll
    for (int rt = 0; rt < 2; ++rt) {  // A-frag: m = j, k = f, scaled by d_j
      const int jl = (rt << 4) + lr;
      const float* xp = X + (size_t)(jb + jl) * INF + f0;
      const float d = sd[jl];
      f32x4 u0 = *(const f32x4*)(xp);
      f32x4 u1 = *(const f32x4*)(xp + 4);
      i32x4 t;
      t.x = (int)pkbf(u0.x * d, u0.y * d); t.y = (int)pkbf(u0.z * d, u0.w * d);
      t.z = (int)pkbf(u1.x * d, u1.y * d); t.w = (int)pkbf(u1.z * d, u1.w * d);
      const s16x8 af = __builtin_bit_cast(s16x8, t);
#pragma unroll
      for (int ct = 0; ct < 4; ++ct)
        acc[rt][ct] = __builtin_amdgcn_mfma_f32_16x16x32_bf16(
            af, bf[ct], acc[rt][ct], 0, 0, 0);
    }
  }

  // D-frag: lane l holds (j = jb + rt*16 + lq*4 + r, o = w*64 + ct*16 + lr)
#pragma unroll
  for (int rt = 0; rt < 2; ++rt)
#pragma unroll
    for (int ct = 0; ct < 4; ++ct) {
      const int o = (w << 6) + (ct << 4) + lr;
      // Ztf: frag(ft = o>>4 = w*4+ct, kb = j>>5 = blockIdx.x);
      // lane' = (o&15) + 16*((j&31)>>3); elem = j&7 -> 4 consecutive (lq&1)*4+r
      const int lane2 = lr + (((rt << 1) + (lq >> 1)) << 4);
      u32x2 p;
      p.x = pkbf(acc[rt][ct].x, acc[rt][ct].y);
      p.y = pkbf(acc[rt][ct].z, acc[rt][ct].w);
      const size_t dst = (((size_t)((w << 2) + ct) << 8) + blockIdx.x) * 512 +
                         (lane2 << 3) + ((lq & 1) << 2);
      *(u32x2*)(Ztf + dst) = p;
      // Zrm: row-major scatter (tiny kernel, 2-B stores)
      const int jrow = jb + (rt << 4) + (lq << 2);
#pragma unroll
      for (int r = 0; r < 4; ++r)
        Zrm[(size_t)(jrow + r) * OUTF + o] = f2bf(acc[rt][ct][r]);
    }
}

// ---------------------------------------------------------------------------
// K3: P[sp] = A[64 rows, ksp] @ Ztf^T  (bf16 MFMA, fp32 acc) — R0 geometry
// (BM=64 BN=256 BK=64, 32 KB LDS) but with __launch_bounds__(256, 3):
// R0/R2/R3 were all flat under schedule + traffic changes => the kernel is
// latency-bound at 2 blocks/CU. 32 KB LDS admits 3 blocks/CU (96/160 KB);
// VGPR cap at 3 waves/EU is ~170, which this kernel fits without spilling.
// More resident waves hide the L2-B-load + LDS-read + barrier latency chain.
// ---------------------------------------------------------------------------
__device__ __forceinline__ s16x8 ldcvt(const float* buf, int n, int kc, int lq) {
  const int base = (n << 6) + (kc << 5);
  const int sw = n & 7;
  f32x4 u0 = *(const f32x4*)(buf + base + ((((lq << 1) | 0) ^ sw) << 2));
  f32x4 u1 = *(const f32x4*)(buf + base + ((((lq << 1) | 1) ^ sw) << 2));
  i32x4 t;
  t.x = (int)pkbf(u0.x, u0.y);
  t.y = (int)pkbf(u0.z, u0.w);
  t.z = (int)pkbf(u1.x, u1.y);
  t.w = (int)pkbf(u1.z, u1.w);
  return __builtin_bit_cast(s16x8, t);
}

__global__ __launch_bounds__(256, 3) void k_gemm(const float* __restrict__ A,
                                                 const short* __restrict__ Ztf,
                                                 float* __restrict__ P,
                                                 int splits) {
  __shared__ float Ab[2 * 4096];  // 2 x (64 rows x 64 floats), chunk-swizzled
  const int tid = threadIdx.x;
  const int w = tid >> 6, l = tid & 63, lr = l & 15, lq = l >> 4;
  const int row0 = (int)blockIdx.x << 6;
  const int sp = blockIdx.y;
  const int kspan = NCOL / splits;
  const int k0 = sp * kspan;
  const int steps = kspan >> 6;

  const char* gA[4];
#pragma unroll
  for (int j = 0; j < 4; ++j) {
    const int p = tid + (j << 8);
    const int n = p >> 4, h = (p >> 3) & 1, cpos = p & 7;
    const int c = cpos ^ (n & 7);
    gA[j] = (const char*)(A + (size_t)(row0 + n) * NCOL + k0 + (h << 5) + (c << 2));
  }
  char* ldst0 = (char*)Ab + ((tid & ~63) << 4);

  // frag-ordered B: frag (ftile = w*4+ct, kb) at Ztf[(ftile*256+kb)*512 + l*8]
  const short* Bw = Ztf + ((size_t)w << 19) + ((size_t)(k0 >> 5) << 9) + (l << 3);

  f32x4 acc[4][4];
#pragma unroll
  for (int rt = 0; rt < 4; ++rt)
#pragma unroll
    for (int ct = 0; ct < 4; ++ct) acc[rt][ct] = (f32x4){0.f, 0.f, 0.f, 0.f};

  // prologue: DMA(0); B(0, kc=0)
#pragma unroll
  for (int j = 0; j < 4; ++j) GLDS(gA[j], ldst0 + (j << 12));
  i32x4 bB0[4];
#pragma unroll
  for (int ct = 0; ct < 4; ++ct)
    bB0[ct] = *(const i32x4*)(Bw + ((size_t)ct << 17));

  for (int s = 0; s < steps; ++s) {
    __syncthreads();  // drains DMA(s) + B-prefetches for step s

    if (s + 1 < steps) {
      char* dst = ldst0 + (((s + 1) & 1) << 14);
      const size_t go = (size_t)(s + 1) << 8;  // 256 B = 64 floats
#pragma unroll
      for (int j = 0; j < 4; ++j) GLDS(gA[j] + go, dst + (j << 12));
    }

    // B(s, kc=1), coalesced
    i32x4 bB1[4];
#pragma unroll
    for (int ct = 0; ct < 4; ++ct)
      bB1[ct] = *(const i32x4*)(Bw + ((size_t)ct << 17) +
                                ((size_t)((s << 1) + 1) << 9));

    const float* buf = Ab + ((s & 1) << 12);

    // ---- kc = 0 ----
    s16x8 af[4];
#pragma unroll
    for (int rt = 0; rt < 4; ++rt) af[rt] = ldcvt(buf, (rt << 4) + lr, 0, lq);
#pragma unroll
    for (int rt = 0; rt < 4; ++rt) {
      const s16x8 a = af[rt];
#pragma unroll
      for (int ct = 0; ct < 4; ++ct)
        acc[rt][ct] = __builtin_amdgcn_mfma_f32_16x16x32_bf16(
            a, __builtin_bit_cast(s16x8, bB0[ct]), acc[rt][ct], 0, 0, 0);
    }

    if (s + 1 < steps) {  // prefetch B(s+1, kc=0)
#pragma unroll
      for (int ct = 0; ct < 4; ++ct)
        bB0[ct] = *(const i32x4*)(Bw + ((size_t)ct << 17) +
                                  ((size_t)((s << 1) + 2) << 9));
    }

    // ---- kc = 1 ----
#pragma unroll
    for (int rt = 0; rt < 4; ++rt) af[rt] = ldcvt(buf, (rt << 4) + lr, 1, lq);
#pragma unroll
    for (int rt = 0; rt < 4; ++rt) {
      const s16x8 a = af[rt];
#pragma unroll
      for (int ct = 0; ct < 4; ++ct)
        acc[rt][ct] = __builtin_amdgcn_mfma_f32_16x16x32_bf16(
            a, __builtin_bit_cast(s16x8, bB1[ct]), acc[rt][ct], 0, 0, 0);
    }
  }

  float* Pp = P + ((size_t)sp << 21);
#pragma unroll
  for (int rt = 0; rt < 4; ++rt)
#pragma unroll
    for (int ct = 0; ct < 4; ++ct) {
      const int col = (w << 6) + (ct << 4) + lr;
      const int row = row0 + (rt << 4) + (lq << 2);
#pragma unroll
      for (int r = 0; r < 4; ++r)
        Pp[((size_t)(row + r) << 8) + col] = acc[rt][ct][r];
    }
}

// ---------------------------------------------------------------------------
// K4: out[i,o] = dis[i]*(sum_sp P + Z[i,o]) + b[o]  — pure coalesced reduce.
// One f32x4 per thread; a wave covers exactly one row (dis wave-uniform).
// ---------------------------------------------------------------------------
__global__ __launch_bounds__(256) void k_fin(const float* __restrict__ P,
                                             const short* __restrict__ Zrm,
                                             const float* __restrict__ dis,
                                             const float* __restrict__ bias,
                                             float* __restrict__ out,
                                             int splits) {
  const int q = (int)blockIdx.x * 256 + threadIdx.x;
  const int i = q >> 6;
  const int o0 = (q & 63) << 2;
  const float di = dis[i];
  const float* p = P + ((size_t)i << 8) + o0;
  f32x4 u = *(const f32x4*)p;
#pragma unroll 3
  for (int sp = 1; sp < 4; ++sp) u += *(const f32x4*)(p + ((size_t)sp << 21));
  u32x2 zz = *(const u32x2*)(Zrm + ((size_t)i << 8) + o0);
  f32x4 z;
  z.x = bf2f((short)(zz.x & 0xFFFF));
  z.y = bf2f((short)(zz.x >> 16));
  z.z = bf2f((short)(zz.y & 0xFFFF));
  z.w = bf2f((short)(zz.y >> 16));
  f32x4 bb = *(const f32x4*)(bias + o0);
  f32x4 r = (u + z) * di + bb;
  *(f32x4*)(out + ((size_t)i << 8) + o0) = r;
}

// ---------------------------------------------------------------------------
extern "C" void kernel_launch(void* const* d_in, const int* in_sizes, int n_in,
                              void* d_out, int out_size, void* d_ws,
                              size_t ws_size, hipStream_t stream) {
  const float* X = (const float*)d_in[0];
  const float* A = (const float*)d_in[1];
  const float* W = (const float*)d_in[2];
  const float* b = (const float*)d_in[3];
  float* out = (float*)d_out;

  char* ws = (char*)d_ws;
  float* dis = (float*)ws;                       // 32 KB
  short* Ztf = (short*)(ws + 32768);             // 4 MB (frag-ordered Z)
  short* Zrm = (short*)(ws + 32768 + 4194304);   // 4 MB (row-major Z)
  float* P = (float*)(ws + 32768 + 2 * 4194304); // 4 x 8 MB split-K partials

  k_deg<<<2048, 256, 0, stream>>>(A, dis);
  k_z<<<256, 256, 0, stream>>>(X, W, dis, Ztf, Zrm);
  k_gemm<<<dim3(128, 4), 256, 0, stream>>>(A, Ztf, P, 4);
  k_fin<<<2048, 256, 0, stream>>>(P, Zrm, dis, b, out, 4);
}